// Round 1
// baseline (912.084 us; speedup 1.0000x reference)
//
#include <hip/hip_runtime.h>
#include <math.h>

#define BM 64
#define BN 64
#define BK 16

// ---------------- CSR build ----------------

__global__ void init_cnt_kernel(int* cnt, int n) {
    int i = blockIdx.x * blockDim.x + threadIdx.x;
    if (i < n) cnt[i] = 0;
}

__global__ void count_kernel(const int* __restrict__ dst, int* __restrict__ cnt, int E) {
    int e = blockIdx.x * blockDim.x + threadIdx.x;
    if (e < E) atomicAdd(&cnt[dst[e]], 1);
}

// Single-block exclusive scan over cnt[0..n) -> rp, also copies to cursor and
// computes dinv[i] = rsqrt(deg) where deg = cnt[i] + 1 (self loop).
__global__ __launch_bounds__(1024) void scan_kernel(const int* __restrict__ cnt,
                                                    int* __restrict__ rp,
                                                    int* __restrict__ cursor,
                                                    float* __restrict__ dinv, int n) {
    __shared__ int sdata[1024];
    int carry = 0;
    for (int base = 0; base < n; base += 1024) {
        int i = base + (int)threadIdx.x;
        int v = (i < n) ? cnt[i] : 0;
        sdata[threadIdx.x] = v;
        __syncthreads();
        for (int off = 1; off < 1024; off <<= 1) {
            int t = 0;
            if ((int)threadIdx.x >= off) t = sdata[threadIdx.x - off];
            __syncthreads();
            sdata[threadIdx.x] += t;
            __syncthreads();
        }
        int incl = sdata[threadIdx.x];
        if (i < n) {
            int excl = carry + incl - v;
            rp[i] = excl;
            cursor[i] = excl;
            dinv[i] = rsqrtf((float)v + 1.0f);
        }
        carry += sdata[1023];
        __syncthreads();
    }
    if (threadIdx.x == 0) rp[n] = carry;
}

__global__ void fill_kernel(const int* __restrict__ src, const int* __restrict__ dst,
                            int* __restrict__ cursor, const float* __restrict__ dinv,
                            int* __restrict__ csrc, float* __restrict__ cw, int E) {
    int e = blockIdx.x * blockDim.x + threadIdx.x;
    if (e >= E) return;
    int d = dst[e];
    int s = src[e];
    int p = atomicAdd(&cursor[d], 1);
    csrc[p] = s;
    cw[p] = dinv[s] * dinv[d];
}

// ---------------- fp32 tiled GEMM: C[MxN] = A[MxK] @ B[KxN] ----------------
// 256 threads, 64x64 tile, each thread 4x4 micro-tile. Guards on M and N edges.
// Requires K % 16 == 0 (holds: 768/256/128).

__global__ __launch_bounds__(256) void sgemm_kernel(const float* __restrict__ A,
                                                    const float* __restrict__ B,
                                                    float* __restrict__ C,
                                                    int M, int N, int K) {
    __shared__ float As[BK][BM + 4];   // transposed A tile: As[k][m]
    __shared__ float Bs[BK][BN];

    int tid = threadIdx.x;
    int tx = tid & 15;   // col group 0..15
    int ty = tid >> 4;   // row group 0..15
    int m0 = blockIdx.y * BM;
    int n0 = blockIdx.x * BN;

    int a_row = tid >> 2;          // 0..63
    int a_k   = (tid & 3) << 2;    // 0,4,8,12
    int b_k   = tid >> 4;          // 0..15
    int b_col = (tid & 15) << 2;   // 0..60

    float acc[4][4] = {};

    for (int k0 = 0; k0 < K; k0 += BK) {
        float4 a = make_float4(0.f, 0.f, 0.f, 0.f);
        int grow = m0 + a_row;
        if (grow < M) a = *(const float4*)&A[(size_t)grow * K + k0 + a_k];
        As[a_k + 0][a_row] = a.x;
        As[a_k + 1][a_row] = a.y;
        As[a_k + 2][a_row] = a.z;
        As[a_k + 3][a_row] = a.w;

        const float* Brow = &B[(size_t)(k0 + b_k) * N];
        int gcol = n0 + b_col;
        float4 b;
        b.x = (gcol + 0 < N) ? Brow[gcol + 0] : 0.f;
        b.y = (gcol + 1 < N) ? Brow[gcol + 1] : 0.f;
        b.z = (gcol + 2 < N) ? Brow[gcol + 2] : 0.f;
        b.w = (gcol + 3 < N) ? Brow[gcol + 3] : 0.f;
        *(float4*)&Bs[b_k][b_col] = b;
        __syncthreads();

#pragma unroll
        for (int k = 0; k < BK; ++k) {
            float4 av = *(const float4*)&As[k][ty << 2];
            float4 bv = *(const float4*)&Bs[k][tx << 2];
            float ar[4] = {av.x, av.y, av.z, av.w};
            float br[4] = {bv.x, bv.y, bv.z, bv.w};
#pragma unroll
            for (int i = 0; i < 4; ++i)
#pragma unroll
                for (int j = 0; j < 4; ++j)
                    acc[i][j] += ar[i] * br[j];
        }
        __syncthreads();
    }

#pragma unroll
    for (int i = 0; i < 4; ++i) {
        int grow = m0 + (ty << 2) + i;
        if (grow >= M) continue;
        int gcol = n0 + (tx << 2);
        if (gcol + 3 < N) {
            float4 v = make_float4(acc[i][0], acc[i][1], acc[i][2], acc[i][3]);
            *(float4*)&C[(size_t)grow * N + gcol] = v;
        } else {
#pragma unroll
            for (int j = 0; j < 4; ++j)
                if (gcol + j < N) C[(size_t)grow * N + gcol + j] = acc[i][j];
        }
    }
}

// ---------------- CSR aggregation: out[i] = sum_e w_e * h[src_e] + dinv[i]^2 * h[i] + b, act ----------------
// One block per node, blockDim.x == C (128 or 256). relu flag applies ReLU.

__global__ void agg_kernel(const float* __restrict__ h, const int* __restrict__ rp,
                           const int* __restrict__ csrc, const float* __restrict__ cw,
                           const float* __restrict__ dinv, const float* __restrict__ bias,
                           float* __restrict__ out, int C, int relu) {
    int node = blockIdx.x;
    int t = threadIdx.x;
    float di = dinv[node];
    float acc = di * di * h[(size_t)node * C + t];
    int e0 = rp[node], e1 = rp[node + 1];
    int e = e0;
    for (; e + 1 < e1; e += 2) {
        int s0 = csrc[e], s1 = csrc[e + 1];
        float w0 = cw[e], w1 = cw[e + 1];
        float v0 = h[(size_t)s0 * C + t];
        float v1 = h[(size_t)s1 * C + t];
        acc += w0 * v0 + w1 * v1;
    }
    if (e < e1) acc += cw[e] * h[(size_t)csrc[e] * C + t];
    float v = acc + bias[t];
    if (relu) v = fmaxf(v, 0.f);
    out[(size_t)node * C + t] = v;
}

// Final layer: C == 2, one thread per node, fused bias + sigmoid.
__global__ void agg3_kernel(const float* __restrict__ h, const int* __restrict__ rp,
                            const int* __restrict__ csrc, const float* __restrict__ cw,
                            const float* __restrict__ dinv, const float* __restrict__ bias,
                            float* __restrict__ out, int n) {
    int node = blockIdx.x * blockDim.x + threadIdx.x;
    if (node >= n) return;
    float di = dinv[node];
    float a0 = di * di * h[2 * (size_t)node];
    float a1 = di * di * h[2 * (size_t)node + 1];
    int e1 = rp[node + 1];
    for (int e = rp[node]; e < e1; ++e) {
        int s = csrc[e];
        float w = cw[e];
        a0 += w * h[2 * (size_t)s];
        a1 += w * h[2 * (size_t)s + 1];
    }
    a0 += bias[0];
    a1 += bias[1];
    out[2 * (size_t)node]     = 1.f / (1.f + __expf(-a0));
    out[2 * (size_t)node + 1] = 1.f / (1.f + __expf(-a1));
}

// ---------------- launch ----------------

extern "C" void kernel_launch(void* const* d_in, const int* in_sizes, int n_in,
                              void* d_out, int out_size, void* d_ws, size_t ws_size,
                              hipStream_t stream) {
    const float* x  = (const float*)d_in[0];
    const int*   ei = (const int*)d_in[1];
    const float* W1 = (const float*)d_in[2];
    const float* b1 = (const float*)d_in[3];
    const float* W2 = (const float*)d_in[4];
    const float* b2 = (const float*)d_in[5];
    const float* W3 = (const float*)d_in[6];
    const float* b3 = (const float*)d_in[7];
    float* out = (float*)d_out;

    const int E  = in_sizes[1] / 2;
    const int C1 = in_sizes[3];              // 256
    const int C2 = in_sizes[5];              // 128
    const int C3 = in_sizes[7];              // 2
    const int K1 = in_sizes[2] / C1;         // 768
    const int N  = in_sizes[0] / K1;         // 50000

    const int* srcv = ei;
    const int* dstv = ei + E;

    char* p = (char*)d_ws;
    auto carve = [&](size_t bytes) {
        char* r = p;
        p += (bytes + 255) & ~(size_t)255;
        return r;
    };
    int*   cnt    = (int*)carve((size_t)N * 4);
    int*   rp     = (int*)carve((size_t)(N + 1) * 4);
    int*   cursor = (int*)carve((size_t)N * 4);
    float* dinv   = (float*)carve((size_t)N * 4);
    int*   csrc   = (int*)carve((size_t)E * 4);
    float* cw     = (float*)carve((size_t)E * 4);
    float* bufA   = (float*)carve((size_t)N * C1 * 4);
    float* bufB   = (float*)carve((size_t)N * C1 * 4);

    // CSR build (shared by all three layers)
    init_cnt_kernel<<<(N + 255) / 256, 256, 0, stream>>>(cnt, N);
    count_kernel<<<(E + 255) / 256, 256, 0, stream>>>(dstv, cnt, E);
    scan_kernel<<<1, 1024, 0, stream>>>(cnt, rp, cursor, dinv, N);
    fill_kernel<<<(E + 255) / 256, 256, 0, stream>>>(srcv, dstv, cursor, dinv, csrc, cw, E);

    // Layer 1: h1 = x @ W1 ; a1 = relu(Ahat h1 + b1)
    dim3 g1((C1 + BN - 1) / BN, (N + BM - 1) / BM);
    sgemm_kernel<<<g1, 256, 0, stream>>>(x, W1, bufA, N, C1, K1);
    agg_kernel<<<N, C1, 0, stream>>>(bufA, rp, csrc, cw, dinv, b1, bufB, C1, 1);

    // Layer 2: h2 = a1 @ W2 ; a2 = relu(Ahat h2 + b2)
    dim3 g2((C2 + BN - 1) / BN, (N + BM - 1) / BM);
    sgemm_kernel<<<g2, 256, 0, stream>>>(bufB, W2, bufA, N, C2, C1);
    agg_kernel<<<N, C2, 0, stream>>>(bufA, rp, csrc, cw, dinv, b2, bufB, C2, 1);

    // Layer 3: h3 = a2 @ W3 ; out = sigmoid(Ahat h3 + b3)
    dim3 g3((C3 + BN - 1) / BN, (N + BM - 1) / BM);
    sgemm_kernel<<<g3, 256, 0, stream>>>(bufB, W3, bufA, N, C3, C2);
    agg3_kernel<<<(N + 255) / 256, 256, 0, stream>>>(bufA, rp, csrc, cw, dinv, b3, out, N);
}

// Round 2
// 681.765 us; speedup vs baseline: 1.3378x; 1.3378x over previous
//
#include <hip/hip_runtime.h>
#include <math.h>

#define BM 64
#define BN 64
#define BK 16

typedef short s16x8 __attribute__((ext_vector_type(8)));
typedef __bf16 b16x8 __attribute__((ext_vector_type(8)));
typedef float f32x4 __attribute__((ext_vector_type(4)));

__device__ inline short f2bf(float f) {
    unsigned u = __float_as_uint(f);
    unsigned r = u + 0x7FFFu + ((u >> 16) & 1u);   // RNE
    return (short)(r >> 16);
}

// ---------------- CSR build ----------------

__global__ void init_cnt_kernel(int* cnt, int n) {
    int i = blockIdx.x * blockDim.x + threadIdx.x;
    if (i < n) cnt[i] = 0;
}

__global__ void count_kernel(const int* __restrict__ dst, int* __restrict__ cnt, int E) {
    int e = blockIdx.x * blockDim.x + threadIdx.x;
    if (e < E) atomicAdd(&cnt[dst[e]], 1);
}

__global__ __launch_bounds__(1024) void scan_kernel(const int* __restrict__ cnt,
                                                    int* __restrict__ rp,
                                                    int* __restrict__ cursor,
                                                    float* __restrict__ dinv, int n) {
    __shared__ int sdata[1024];
    int carry = 0;
    for (int base = 0; base < n; base += 1024) {
        int i = base + (int)threadIdx.x;
        int v = (i < n) ? cnt[i] : 0;
        sdata[threadIdx.x] = v;
        __syncthreads();
        for (int off = 1; off < 1024; off <<= 1) {
            int t = 0;
            if ((int)threadIdx.x >= off) t = sdata[threadIdx.x - off];
            __syncthreads();
            sdata[threadIdx.x] += t;
            __syncthreads();
        }
        int incl = sdata[threadIdx.x];
        if (i < n) {
            int excl = carry + incl - v;
            rp[i] = excl;
            cursor[i] = excl;
            dinv[i] = rsqrtf((float)v + 1.0f);
        }
        carry += sdata[1023];
        __syncthreads();
    }
    if (threadIdx.x == 0) rp[n] = carry;
}

__global__ void fill_kernel(const int* __restrict__ src, const int* __restrict__ dst,
                            int* __restrict__ cursor, const float* __restrict__ dinv,
                            int* __restrict__ csrc, float* __restrict__ cw, int E) {
    int e = blockIdx.x * blockDim.x + threadIdx.x;
    if (e >= E) return;
    int d = dst[e];
    int s = src[e];
    int p = atomicAdd(&cursor[d], 1);
    csrc[p] = s;
    cw[p] = dinv[s] * dinv[d];
}

// ---------------- weight pre-transpose to fragment-ready bf16 ----------------
// Wt chunk layout: [c = k0/32][b = n0/128][nt 0..7][lane 0..63][j 0..7]
//   value = W[c*32 + (lane>>4)*8 + j][b*128 + nt*16 + (lane&15)]

__global__ void make_wt_kernel(const float* __restrict__ W, short* __restrict__ Wt,
                               int K, int N) {
    int idx = blockIdx.x * blockDim.x + threadIdx.x;
    if (idx >= K * N) return;
    int NB = N >> 7;
    int j = idx & 7;
    int l = (idx >> 3) & 63;
    int nt = (idx >> 9) & 7;
    int rest = idx >> 12;
    int b = rest % NB;
    int c = rest / NB;
    int k = c * 32 + (l >> 4) * 8 + j;
    int n = b * 128 + nt * 16 + (l & 15);
    Wt[idx] = f2bf(W[(size_t)k * N + n]);
}

// ---------------- bf16 MFMA GEMM: C[MxN] = A[MxK] @ B[KxN] ----------------
// A fp32 row-major (converted to bf16 in staging); B pre-transposed bf16 (Wt).
// 128x128 block tile, 256 threads = 4 waves, 64x64 per wave (4x4 16x16x32 mfma).
// Requires K % 32 == 0, N % 128 == 0.

__global__ __launch_bounds__(256) void mfma_gemm_kernel(const float* __restrict__ A,
                                                        const short* __restrict__ Wt,
                                                        float* __restrict__ C,
                                                        int M, int N, int K) {
    __shared__ b16x8 Asl[8 * 64];   // [m_tile][q*16 + m_local] -> 8 bf16, 8 KB
    __shared__ b16x8 Bsl[8 * 64];   // [n_tile][q*16 + nl]      -> 8 bf16, 8 KB

    const int tid = threadIdx.x;
    const int lane = tid & 63;
    const int wave = tid >> 6;
    const int wm = wave & 1;        // row half of 128 tile
    const int wn = wave >> 1;       // col half
    const int NB = N >> 7;
    const int m0 = blockIdx.y * 128;
    const int n0 = blockIdx.x * 128;
    const int KC = K >> 5;          // number of 32-wide K chunks

    f32x4 acc[4][4];
#pragma unroll
    for (int i = 0; i < 4; ++i)
#pragma unroll
        for (int j = 0; j < 4; ++j)
            acc[i][j] = (f32x4){0.f, 0.f, 0.f, 0.f};

    for (int c = 0; c < KC; ++c) {
        const int k0 = c << 5;
        // ---- stage A: 128 rows x 32 k, fp32 -> bf16, fragment-ready ----
#pragma unroll
        for (int u = 0; u < 2; ++u) {
            int unit = tid + u * 256;          // 0..511
            int r = unit >> 2;                 // 0..127
            int q = unit & 3;                  // k octet
            int grow = m0 + r;
            float4 f0 = make_float4(0.f, 0.f, 0.f, 0.f);
            float4 f1 = make_float4(0.f, 0.f, 0.f, 0.f);
            if (grow < M) {
                const float* ap = &A[(size_t)grow * K + k0 + q * 8];
                f0 = *(const float4*)ap;
                f1 = *(const float4*)(ap + 4);
            }
            s16x8 v;
            v[0] = f2bf(f0.x); v[1] = f2bf(f0.y); v[2] = f2bf(f0.z); v[3] = f2bf(f0.w);
            v[4] = f2bf(f1.x); v[5] = f2bf(f1.y); v[6] = f2bf(f1.z); v[7] = f2bf(f1.w);
            int m_tile = r >> 4;
            int lane_w = q * 16 + (r & 15);
            Asl[m_tile * 64 + lane_w] = __builtin_bit_cast(b16x8, v);
        }
        // ---- stage B: copy 8 KB fragment-ready chunk ----
        {
            const s16x8* wt = (const s16x8*)(Wt + ((size_t)(c * NB + blockIdx.x) << 12));
            Bsl[tid] = __builtin_bit_cast(b16x8, wt[tid]);
            Bsl[tid + 256] = __builtin_bit_cast(b16x8, wt[tid + 256]);
        }
        __syncthreads();

        b16x8 areg[4], breg[4];
#pragma unroll
        for (int i = 0; i < 4; ++i) areg[i] = Asl[(wm * 4 + i) * 64 + lane];
#pragma unroll
        for (int j = 0; j < 4; ++j) breg[j] = Bsl[(wn * 4 + j) * 64 + lane];
#pragma unroll
        for (int i = 0; i < 4; ++i)
#pragma unroll
            for (int j = 0; j < 4; ++j)
                acc[i][j] = __builtin_amdgcn_mfma_f32_16x16x32_bf16(areg[i], breg[j], acc[i][j], 0, 0, 0);
        __syncthreads();
    }

    // ---- store: row = quad*4 + reg, col = lane&15 ----
    const int quad = lane >> 4;
    const int nl = lane & 15;
#pragma unroll
    for (int i = 0; i < 4; ++i) {
        int rbase = m0 + wm * 64 + i * 16 + quad * 4;
#pragma unroll
        for (int j = 0; j < 4; ++j) {
            int col = n0 + wn * 64 + j * 16 + nl;
#pragma unroll
            for (int r = 0; r < 4; ++r) {
                int row = rbase + r;
                if (row < M) C[(size_t)row * N + col] = acc[i][j][r];
            }
        }
    }
}

// ---------------- fp32 tiled GEMM (kept for layer 3, N=2) ----------------

__global__ __launch_bounds__(256) void sgemm_kernel(const float* __restrict__ A,
                                                    const float* __restrict__ B,
                                                    float* __restrict__ C,
                                                    int M, int N, int K) {
    __shared__ float As[BK][BM + 4];
    __shared__ float Bs[BK][BN];

    int tid = threadIdx.x;
    int tx = tid & 15;
    int ty = tid >> 4;
    int m0 = blockIdx.y * BM;
    int n0 = blockIdx.x * BN;

    int a_row = tid >> 2;
    int a_k   = (tid & 3) << 2;
    int b_k   = tid >> 4;
    int b_col = (tid & 15) << 2;

    float acc[4][4] = {};

    for (int k0 = 0; k0 < K; k0 += BK) {
        float4 a = make_float4(0.f, 0.f, 0.f, 0.f);
        int grow = m0 + a_row;
        if (grow < M) a = *(const float4*)&A[(size_t)grow * K + k0 + a_k];
        As[a_k + 0][a_row] = a.x;
        As[a_k + 1][a_row] = a.y;
        As[a_k + 2][a_row] = a.z;
        As[a_k + 3][a_row] = a.w;

        const float* Brow = &B[(size_t)(k0 + b_k) * N];
        int gcol = n0 + b_col;
        float4 b;
        b.x = (gcol + 0 < N) ? Brow[gcol + 0] : 0.f;
        b.y = (gcol + 1 < N) ? Brow[gcol + 1] : 0.f;
        b.z = (gcol + 2 < N) ? Brow[gcol + 2] : 0.f;
        b.w = (gcol + 3 < N) ? Brow[gcol + 3] : 0.f;
        *(float4*)&Bs[b_k][b_col] = b;
        __syncthreads();

#pragma unroll
        for (int k = 0; k < BK; ++k) {
            float4 av = *(const float4*)&As[k][ty << 2];
            float4 bv = *(const float4*)&Bs[k][tx << 2];
            float ar[4] = {av.x, av.y, av.z, av.w};
            float br[4] = {bv.x, bv.y, bv.z, bv.w};
#pragma unroll
            for (int i = 0; i < 4; ++i)
#pragma unroll
                for (int j = 0; j < 4; ++j)
                    acc[i][j] += ar[i] * br[j];
        }
        __syncthreads();
    }

#pragma unroll
    for (int i = 0; i < 4; ++i) {
        int grow = m0 + (ty << 2) + i;
        if (grow >= M) continue;
        int gcol = n0 + (tx << 2);
        if (gcol + 3 < N) {
            float4 v = make_float4(acc[i][0], acc[i][1], acc[i][2], acc[i][3]);
            *(float4*)&C[(size_t)grow * N + gcol] = v;
        } else {
#pragma unroll
            for (int j = 0; j < 4; ++j)
                if (gcol + j < N) C[(size_t)grow * N + gcol + j] = acc[i][j];
        }
    }
}

// ---------------- CSR aggregation ----------------

__global__ void agg_kernel(const float* __restrict__ h, const int* __restrict__ rp,
                           const int* __restrict__ csrc, const float* __restrict__ cw,
                           const float* __restrict__ dinv, const float* __restrict__ bias,
                           float* __restrict__ out, int C, int relu) {
    int node = blockIdx.x;
    int t = threadIdx.x;
    float di = dinv[node];
    float acc = di * di * h[(size_t)node * C + t];
    int e0 = rp[node], e1 = rp[node + 1];
    int e = e0;
    for (; e + 1 < e1; e += 2) {
        int s0 = csrc[e], s1 = csrc[e + 1];
        float w0 = cw[e], w1 = cw[e + 1];
        float v0 = h[(size_t)s0 * C + t];
        float v1 = h[(size_t)s1 * C + t];
        acc += w0 * v0 + w1 * v1;
    }
    if (e < e1) acc += cw[e] * h[(size_t)csrc[e] * C + t];
    float v = acc + bias[t];
    if (relu) v = fmaxf(v, 0.f);
    out[(size_t)node * C + t] = v;
}

__global__ void agg3_kernel(const float* __restrict__ h, const int* __restrict__ rp,
                            const int* __restrict__ csrc, const float* __restrict__ cw,
                            const float* __restrict__ dinv, const float* __restrict__ bias,
                            float* __restrict__ out, int n) {
    int node = blockIdx.x * blockDim.x + threadIdx.x;
    if (node >= n) return;
    float di = dinv[node];
    float a0 = di * di * h[2 * (size_t)node];
    float a1 = di * di * h[2 * (size_t)node + 1];
    int e1 = rp[node + 1];
    for (int e = rp[node]; e < e1; ++e) {
        int s = csrc[e];
        float w = cw[e];
        a0 += w * h[2 * (size_t)s];
        a1 += w * h[2 * (size_t)s + 1];
    }
    a0 += bias[0];
    a1 += bias[1];
    out[2 * (size_t)node]     = 1.f / (1.f + __expf(-a0));
    out[2 * (size_t)node + 1] = 1.f / (1.f + __expf(-a1));
}

// ---------------- launch ----------------

extern "C" void kernel_launch(void* const* d_in, const int* in_sizes, int n_in,
                              void* d_out, int out_size, void* d_ws, size_t ws_size,
                              hipStream_t stream) {
    const float* x  = (const float*)d_in[0];
    const int*   ei = (const int*)d_in[1];
    const float* W1 = (const float*)d_in[2];
    const float* b1 = (const float*)d_in[3];
    const float* W2 = (const float*)d_in[4];
    const float* b2 = (const float*)d_in[5];
    const float* W3 = (const float*)d_in[6];
    const float* b3 = (const float*)d_in[7];
    float* out = (float*)d_out;

    const int E  = in_sizes[1] / 2;
    const int C1 = in_sizes[3];              // 256
    const int C2 = in_sizes[5];              // 128
    const int C3 = in_sizes[7];              // 2
    const int K1 = in_sizes[2] / C1;         // 768
    const int N  = in_sizes[0] / K1;         // 50000

    const int* srcv = ei;
    const int* dstv = ei + E;

    char* p = (char*)d_ws;
    auto carve = [&](size_t bytes) {
        char* r = p;
        p += (bytes + 255) & ~(size_t)255;
        return r;
    };
    int*   cnt    = (int*)carve((size_t)N * 4);
    int*   rp     = (int*)carve((size_t)(N + 1) * 4);
    int*   cursor = (int*)carve((size_t)N * 4);
    float* dinv   = (float*)carve((size_t)N * 4);
    int*   csrc   = (int*)carve((size_t)E * 4);
    float* cw     = (float*)carve((size_t)E * 4);
    short* Wt1    = (short*)carve((size_t)K1 * C1 * 2);
    short* Wt2    = (short*)carve((size_t)C1 * C2 * 2);
    float* bufA   = (float*)carve((size_t)N * C1 * 4);
    float* bufB   = (float*)carve((size_t)N * C1 * 4);

    // CSR build (shared by all three layers)
    init_cnt_kernel<<<(N + 255) / 256, 256, 0, stream>>>(cnt, N);
    count_kernel<<<(E + 255) / 256, 256, 0, stream>>>(dstv, cnt, E);
    scan_kernel<<<1, 1024, 0, stream>>>(cnt, rp, cursor, dinv, N);
    fill_kernel<<<(E + 255) / 256, 256, 0, stream>>>(srcv, dstv, cursor, dinv, csrc, cw, E);

    // Weight pre-transpose (fragment-ready bf16)
    make_wt_kernel<<<(K1 * C1 + 255) / 256, 256, 0, stream>>>(W1, Wt1, K1, C1);
    make_wt_kernel<<<(C1 * C2 + 255) / 256, 256, 0, stream>>>(W2, Wt2, C1, C2);

    // Layer 1: h1 = x @ W1 (bf16 MFMA) ; a1 = relu(Ahat h1 + b1)
    dim3 g1(C1 / 128, (N + 127) / 128);
    mfma_gemm_kernel<<<g1, 256, 0, stream>>>(x, Wt1, bufA, N, C1, K1);
    agg_kernel<<<N, C1, 0, stream>>>(bufA, rp, csrc, cw, dinv, b1, bufB, C1, 1);

    // Layer 2: h2 = a1 @ W2 (bf16 MFMA) ; a2 = relu(Ahat h2 + b2)
    dim3 g2(C2 / 128, (N + 127) / 128);
    mfma_gemm_kernel<<<g2, 256, 0, stream>>>(bufB, Wt2, bufA, N, C2, C1);
    agg_kernel<<<N, C2, 0, stream>>>(bufA, rp, csrc, cw, dinv, b2, bufB, C2, 1);

    // Layer 3: h3 = a2 @ W3 (fp32, N=2) ; out = sigmoid(Ahat h3 + b3)
    dim3 g3((C3 + BN - 1) / BN, (N + BM - 1) / BM);
    sgemm_kernel<<<g3, 256, 0, stream>>>(bufB, W3, bufA, N, C3, C2);
    agg3_kernel<<<(N + 255) / 256, 256, 0, stream>>>(bufA, rp, csrc, cw, dinv, b3, out, N);
}

// Round 3
// 561.939 us; speedup vs baseline: 1.6231x; 1.2132x over previous
//
#include <hip/hip_runtime.h>
#include <math.h>

typedef short s16x8 __attribute__((ext_vector_type(8)));
typedef __bf16 b16x8 __attribute__((ext_vector_type(8)));
typedef float f32x4 __attribute__((ext_vector_type(4)));

__device__ inline short f2bf(float f) {
    unsigned u = __float_as_uint(f);
    unsigned r = u + 0x7FFFu + ((u >> 16) & 1u);   // RNE
    return (short)(r >> 16);
}
__device__ inline float bf2f(unsigned short u) {
    return __uint_as_float(((unsigned)u) << 16);
}

// ---------------- CSR build ----------------

__global__ void init_cnt_kernel(int* cnt, int n) {
    int i = blockIdx.x * blockDim.x + threadIdx.x;
    if (i < n) cnt[i] = 0;
}

__global__ void count_kernel(const int* __restrict__ dst, int* __restrict__ cnt, int E) {
    int e = blockIdx.x * blockDim.x + threadIdx.x;
    if (e < E) atomicAdd(&cnt[dst[e]], 1);
}

// Hierarchical scan: per-block scan -> wave scan of block sums -> fixup.
__global__ __launch_bounds__(1024) void blockscan_kernel(const int* __restrict__ cnt,
                                                         int* __restrict__ rp,
                                                         int* __restrict__ bsum, int n) {
    __shared__ int sdata[1024];
    int tid = threadIdx.x;
    int i = blockIdx.x * 1024 + tid;
    int v = (i < n) ? cnt[i] : 0;
    sdata[tid] = v;
    __syncthreads();
    for (int off = 1; off < 1024; off <<= 1) {
        int t = 0;
        if (tid >= off) t = sdata[tid - off];
        __syncthreads();
        sdata[tid] += t;
        __syncthreads();
    }
    if (i < n) rp[i] = sdata[tid] - v;       // local exclusive
    if (tid == 1023) bsum[blockIdx.x] = sdata[1023];
}

__global__ void topscan_kernel(int* bsum, int nb) {
    int lane = threadIdx.x;                   // 64 threads
    int carry = 0;
    for (int base = 0; base < nb; base += 64) {
        int idx = base + lane;
        int orig = (idx < nb) ? bsum[idx] : 0;
        int v = orig;
        for (int off = 1; off < 64; off <<= 1) {
            int t = __shfl_up(v, off, 64);
            if (lane >= off) v += t;
        }
        if (idx < nb) bsum[idx] = carry + v - orig;   // exclusive
        carry += __shfl(v, 63, 64);
    }
}

__global__ __launch_bounds__(1024) void fixup_kernel(int* __restrict__ rp,
                                                     const int* __restrict__ bsum,
                                                     const int* __restrict__ cnt,
                                                     int* __restrict__ cursor,
                                                     float* __restrict__ dinv,
                                                     int n, int E) {
    int i = blockIdx.x * 1024 + threadIdx.x;
    if (i < n) {
        int r = rp[i] + bsum[blockIdx.x];
        rp[i] = r;
        cursor[i] = r;
        dinv[i] = rsqrtf((float)cnt[i] + 1.0f);
    }
    if (i == 0) rp[n] = E;
}

__global__ void fill_kernel(const int* __restrict__ src, const int* __restrict__ dst,
                            int* __restrict__ cursor, const float* __restrict__ dinv,
                            int* __restrict__ csrc, float* __restrict__ cw, int E) {
    int e = blockIdx.x * blockDim.x + threadIdx.x;
    if (e >= E) return;
    int d = dst[e];
    int s = src[e];
    int p = atomicAdd(&cursor[d], 1);
    csrc[p] = s;
    cw[p] = dinv[s] * dinv[d];
}

// ---------------- weight pre-transpose to fragment-ready bf16 ----------------
// Wt chunk layout: [c = k0/32][b = n0/128][nt 0..7][lane 0..63][j 0..7]
//   value = W[c*32 + (lane>>4)*8 + j][b*128 + nt*16 + (lane&15)]

__global__ void make_wt_kernel(const float* __restrict__ W, short* __restrict__ Wt,
                               int K, int N) {
    int idx = blockIdx.x * blockDim.x + threadIdx.x;
    if (idx >= K * N) return;
    int NB = N >> 7;
    int j = idx & 7;
    int l = (idx >> 3) & 63;
    int nt = (idx >> 9) & 7;
    int rest = idx >> 12;
    int b = rest % NB;
    int c = rest / NB;
    int k = c * 32 + (l >> 4) * 8 + j;
    int n = b * 128 + nt * 16 + (l & 15);
    Wt[idx] = f2bf(W[(size_t)k * N + n]);
}

// ---------------- bf16 MFMA GEMM: Cb[MxN](bf16) = A[MxK] @ B[KxN] ----------------
// AT = float (fp32 A, converted in staging) or ushort (bf16 A).
// Block 256 threads = 4 waves (wm = wave&1, wn = wave>>1). Wave tile: 64 x (WNT*16).
// Block tile: 128 x (2*WNT*16). Requires K%32==0, N % (2*WNT*16) == 0.

template<typename AT, int WNT>
__global__ __launch_bounds__(256) void mfma_gemm_kernel(const AT* __restrict__ A,
                                                        const short* __restrict__ Wt,
                                                        unsigned short* __restrict__ Cb,
                                                        int M, int N, int K) {
    constexpr int TB = 2 * WNT;                  // B n-tiles per block
    __shared__ b16x8 Asl[8 * 64];                // 8 KB
    __shared__ b16x8 Bsl[TB * 64];               // TB KB

    const int tid = threadIdx.x;
    const int lane = tid & 63;
    const int wave = tid >> 6;
    const int wm = wave & 1;
    const int wn = wave >> 1;
    const int NB = N >> 7;
    const int m0 = blockIdx.y * 128;
    const int n0 = blockIdx.x * (TB * 16);
    const int KC = K >> 5;

    f32x4 acc[4][WNT];
#pragma unroll
    for (int i = 0; i < 4; ++i)
#pragma unroll
        for (int j = 0; j < WNT; ++j)
            acc[i][j] = (f32x4){0.f, 0.f, 0.f, 0.f};

    for (int c = 0; c < KC; ++c) {
        const int k0 = c << 5;
        // ---- stage A: 128 rows x 32 k, fragment-ready ----
#pragma unroll
        for (int u = 0; u < 2; ++u) {
            int unit = tid + u * 256;            // 0..511
            int r = unit >> 2;                   // 0..127
            int q = unit & 3;                    // k octet
            int grow = m0 + r;
            s16x8 v;
            if constexpr (sizeof(AT) == 4) {
                float4 f0 = make_float4(0.f, 0.f, 0.f, 0.f);
                float4 f1 = make_float4(0.f, 0.f, 0.f, 0.f);
                if (grow < M) {
                    const float* ap = (const float*)&A[(size_t)grow * K + k0 + q * 8];
                    f0 = *(const float4*)ap;
                    f1 = *(const float4*)(ap + 4);
                }
                v[0] = f2bf(f0.x); v[1] = f2bf(f0.y); v[2] = f2bf(f0.z); v[3] = f2bf(f0.w);
                v[4] = f2bf(f1.x); v[5] = f2bf(f1.y); v[6] = f2bf(f1.z); v[7] = f2bf(f1.w);
            } else {
                if (grow < M) v = *(const s16x8*)&A[(size_t)grow * K + k0 + q * 8];
                else v = (s16x8){0, 0, 0, 0, 0, 0, 0, 0};
            }
            Asl[(r >> 4) * 64 + q * 16 + (r & 15)] = __builtin_bit_cast(b16x8, v);
        }
        // ---- stage B ----
        {
            const s16x8* wt = (const s16x8*)Wt;
#pragma unroll
            for (int t = tid; t < TB * 64; t += 256) {
                int tile = t >> 6;
                int l = t & 63;
                size_t chunk = (size_t)(c * NB + blockIdx.x * (TB >> 3) + (tile >> 3));
                Bsl[t] = __builtin_bit_cast(b16x8, wt[chunk * 512 + (tile & 7) * 64 + l]);
            }
        }
        __syncthreads();

        b16x8 areg[4], breg[WNT];
#pragma unroll
        for (int i = 0; i < 4; ++i) areg[i] = Asl[(wm * 4 + i) * 64 + lane];
#pragma unroll
        for (int j = 0; j < WNT; ++j) breg[j] = Bsl[(wn * WNT + j) * 64 + lane];
#pragma unroll
        for (int i = 0; i < 4; ++i)
#pragma unroll
            for (int j = 0; j < WNT; ++j)
                acc[i][j] = __builtin_amdgcn_mfma_f32_16x16x32_bf16(areg[i], breg[j], acc[i][j], 0, 0, 0);
        __syncthreads();
    }

    const int quad = lane >> 4;
    const int nl = lane & 15;
#pragma unroll
    for (int i = 0; i < 4; ++i) {
        int rbase = m0 + wm * 64 + i * 16 + quad * 4;
#pragma unroll
        for (int j = 0; j < WNT; ++j) {
            int col = n0 + wn * (WNT * 16) + j * 16 + nl;
#pragma unroll
            for (int r = 0; r < 4; ++r) {
                int row = rbase + r;
                if (row < M) Cb[(size_t)row * N + col] = (unsigned short)f2bf(acc[i][j][r]);
            }
        }
    }
}

// ---------------- aggregation, bf16 in ----------------
// Wave per node. C=256: lane handles 4 channels (ushort4, 8B loads). ReLU, bf16 out.

__global__ __launch_bounds__(256) void agg256_kernel(const unsigned short* __restrict__ h,
                                                     const int* __restrict__ rp,
                                                     const int* __restrict__ csrc,
                                                     const float* __restrict__ cw,
                                                     const float* __restrict__ dinv,
                                                     const float* __restrict__ bias,
                                                     unsigned short* __restrict__ out, int n) {
    int node = blockIdx.x * 4 + (threadIdx.x >> 6);
    int lane = threadIdx.x & 63;
    if (node >= n) return;
    const ushort4* hp = (const ushort4*)h;       // 64 per row
    float di = dinv[node];
    float ws = di * di;
    ushort4 sv = hp[(size_t)node * 64 + lane];
    float a0 = ws * bf2f(sv.x), a1 = ws * bf2f(sv.y), a2 = ws * bf2f(sv.z), a3 = ws * bf2f(sv.w);
    int e = rp[node], e1 = rp[node + 1];
    for (; e + 1 < e1; e += 2) {
        int s0 = csrc[e], s1 = csrc[e + 1];
        float w0 = cw[e], w1 = cw[e + 1];
        ushort4 v0 = hp[(size_t)s0 * 64 + lane];
        ushort4 v1 = hp[(size_t)s1 * 64 + lane];
        a0 += w0 * bf2f(v0.x) + w1 * bf2f(v1.x);
        a1 += w0 * bf2f(v0.y) + w1 * bf2f(v1.y);
        a2 += w0 * bf2f(v0.z) + w1 * bf2f(v1.z);
        a3 += w0 * bf2f(v0.w) + w1 * bf2f(v1.w);
    }
    if (e < e1) {
        int s0 = csrc[e];
        float w0 = cw[e];
        ushort4 v0 = hp[(size_t)s0 * 64 + lane];
        a0 += w0 * bf2f(v0.x); a1 += w0 * bf2f(v0.y);
        a2 += w0 * bf2f(v0.z); a3 += w0 * bf2f(v0.w);
    }
    float4 bv = *(const float4*)&bias[lane * 4];
    a0 = fmaxf(a0 + bv.x, 0.f); a1 = fmaxf(a1 + bv.y, 0.f);
    a2 = fmaxf(a2 + bv.z, 0.f); a3 = fmaxf(a3 + bv.w, 0.f);
    ushort4 ov;
    ov.x = (unsigned short)f2bf(a0); ov.y = (unsigned short)f2bf(a1);
    ov.z = (unsigned short)f2bf(a2); ov.w = (unsigned short)f2bf(a3);
    ((ushort4*)out)[(size_t)node * 64 + lane] = ov;
}

// C=128: lane handles 2 channels (uint loads). Fused: a2 = relu(agg+b2); z = a2 @ W3 (128x2).
__global__ __launch_bounds__(256) void agg128_w3_kernel(const unsigned short* __restrict__ h,
                                                        const int* __restrict__ rp,
                                                        const int* __restrict__ csrc,
                                                        const float* __restrict__ cw,
                                                        const float* __restrict__ dinv,
                                                        const float* __restrict__ b2,
                                                        const float* __restrict__ W3,
                                                        float* __restrict__ z, int n) {
    int node = blockIdx.x * 4 + (threadIdx.x >> 6);
    int lane = threadIdx.x & 63;
    if (node >= n) return;
    const unsigned* hp = (const unsigned*)h;     // 64 uints per row (2 bf16 each)
    float di = dinv[node];
    float ws = di * di;
    unsigned sv = hp[(size_t)node * 64 + lane];
    float a0 = ws * __uint_as_float(sv << 16);
    float a1 = ws * __uint_as_float(sv & 0xFFFF0000u);
    int e = rp[node], e1 = rp[node + 1];
    for (; e + 1 < e1; e += 2) {
        int s0 = csrc[e], s1 = csrc[e + 1];
        float w0 = cw[e], w1 = cw[e + 1];
        unsigned v0 = hp[(size_t)s0 * 64 + lane];
        unsigned v1 = hp[(size_t)s1 * 64 + lane];
        a0 += w0 * __uint_as_float(v0 << 16) + w1 * __uint_as_float(v1 << 16);
        a1 += w0 * __uint_as_float(v0 & 0xFFFF0000u) + w1 * __uint_as_float(v1 & 0xFFFF0000u);
    }
    if (e < e1) {
        int s0 = csrc[e];
        float w0 = cw[e];
        unsigned v0 = hp[(size_t)s0 * 64 + lane];
        a0 += w0 * __uint_as_float(v0 << 16);
        a1 += w0 * __uint_as_float(v0 & 0xFFFF0000u);
    }
    float2 bv = *(const float2*)&b2[lane * 2];
    a0 = fmaxf(a0 + bv.x, 0.f);
    a1 = fmaxf(a1 + bv.y, 0.f);
    // W3 row-major [128][2]; channels 2*lane, 2*lane+1
    float4 wv = *(const float4*)&W3[lane * 4];
    float z0 = a0 * wv.x + a1 * wv.z;
    float z1 = a0 * wv.y + a1 * wv.w;
    for (int off = 32; off > 0; off >>= 1) {
        z0 += __shfl_down(z0, off, 64);
        z1 += __shfl_down(z1, off, 64);
    }
    if (lane == 0) {
        z[2 * (size_t)node] = z0;
        z[2 * (size_t)node + 1] = z1;
    }
}

// Final: out = sigmoid(Ahat z + b3), z fp32 [n][2].
__global__ void agg3_kernel(const float* __restrict__ z, const int* __restrict__ rp,
                            const int* __restrict__ csrc, const float* __restrict__ cw,
                            const float* __restrict__ dinv, const float* __restrict__ bias,
                            float* __restrict__ out, int n) {
    int node = blockIdx.x * blockDim.x + threadIdx.x;
    if (node >= n) return;
    float di = dinv[node];
    float a0 = di * di * z[2 * (size_t)node];
    float a1 = di * di * z[2 * (size_t)node + 1];
    int e1 = rp[node + 1];
    for (int e = rp[node]; e < e1; ++e) {
        int s = csrc[e];
        float w = cw[e];
        a0 += w * z[2 * (size_t)s];
        a1 += w * z[2 * (size_t)s + 1];
    }
    a0 += bias[0];
    a1 += bias[1];
    out[2 * (size_t)node]     = 1.f / (1.f + __expf(-a0));
    out[2 * (size_t)node + 1] = 1.f / (1.f + __expf(-a1));
}

// ---------------- launch ----------------

extern "C" void kernel_launch(void* const* d_in, const int* in_sizes, int n_in,
                              void* d_out, int out_size, void* d_ws, size_t ws_size,
                              hipStream_t stream) {
    const float* x  = (const float*)d_in[0];
    const int*   ei = (const int*)d_in[1];
    const float* W1 = (const float*)d_in[2];
    const float* b1 = (const float*)d_in[3];
    const float* W2 = (const float*)d_in[4];
    const float* b2 = (const float*)d_in[5];
    const float* W3 = (const float*)d_in[6];
    const float* b3 = (const float*)d_in[7];
    float* out = (float*)d_out;

    const int E  = in_sizes[1] / 2;
    const int C1 = in_sizes[3];              // 256
    const int C2 = in_sizes[5];              // 128
    const int K1 = in_sizes[2] / C1;         // 768
    const int N  = in_sizes[0] / K1;         // 50000

    const int* srcv = ei;
    const int* dstv = ei + E;

    char* p = (char*)d_ws;
    auto carve = [&](size_t bytes) {
        char* r = p;
        p += (bytes + 255) & ~(size_t)255;
        return r;
    };
    int*   cnt    = (int*)carve((size_t)N * 4);
    int*   rp     = (int*)carve((size_t)(N + 1) * 4);
    int*   cursor = (int*)carve((size_t)N * 4);
    float* dinv   = (float*)carve((size_t)N * 4);
    int*   bsum   = (int*)carve(1024 * 4);
    int*   csrc   = (int*)carve((size_t)E * 4);
    float* cw     = (float*)carve((size_t)E * 4);
    short* Wt1    = (short*)carve((size_t)K1 * C1 * 2);
    short* Wt2    = (short*)carve((size_t)C1 * C2 * 2);
    unsigned short* hA = (unsigned short*)carve((size_t)N * C1 * 2);
    unsigned short* hB = (unsigned short*)carve((size_t)N * C1 * 2);
    float* zbuf   = (float*)carve((size_t)N * 2 * 4);

    const int nb = (N + 1023) / 1024;

    // CSR build
    init_cnt_kernel<<<(N + 255) / 256, 256, 0, stream>>>(cnt, N);
    count_kernel<<<(E + 255) / 256, 256, 0, stream>>>(dstv, cnt, E);
    blockscan_kernel<<<nb, 1024, 0, stream>>>(cnt, rp, bsum, N);
    topscan_kernel<<<1, 64, 0, stream>>>(bsum, nb);
    fixup_kernel<<<nb, 1024, 0, stream>>>(rp, bsum, cnt, cursor, dinv, N, E);
    fill_kernel<<<(E + 255) / 256, 256, 0, stream>>>(srcv, dstv, cursor, dinv, csrc, cw, E);

    // Weight pre-transpose (fragment-ready bf16)
    make_wt_kernel<<<(K1 * C1 + 255) / 256, 256, 0, stream>>>(W1, Wt1, K1, C1);
    make_wt_kernel<<<(C1 * C2 + 255) / 256, 256, 0, stream>>>(W2, Wt2, C1, C2);

    // Layer 1: h1 = x @ W1 (128x256 tile, fp32 A) ; a1 = relu(Ahat h1 + b1)
    dim3 g1(C1 / 256, (N + 127) / 128);
    mfma_gemm_kernel<float, 8><<<g1, 256, 0, stream>>>(x, Wt1, hA, N, C1, K1);
    agg256_kernel<<<(N + 3) / 4, 256, 0, stream>>>(hA, rp, csrc, cw, dinv, b1, hB, N);

    // Layer 2: h2 = a1 @ W2 (128x128 tile, bf16 A) ; fused a2 = relu(Ahat h2 + b2), z = a2 @ W3
    dim3 g2(C2 / 128, (N + 127) / 128);
    mfma_gemm_kernel<unsigned short, 4><<<g2, 256, 0, stream>>>(hB, Wt2, hA, N, C2, C1);
    agg128_w3_kernel<<<(N + 3) / 4, 256, 0, stream>>>(hA, rp, csrc, cw, dinv, b2, W3, zbuf, N);

    // Layer 3 aggregation + sigmoid
    agg3_kernel<<<(N + 255) / 256, 256, 0, stream>>>(zbuf, rp, csrc, cw, dinv, b3, out, N);
}

// Round 4
// 513.513 us; speedup vs baseline: 1.7762x; 1.0943x over previous
//
#include <hip/hip_runtime.h>
#include <math.h>

typedef short s16x8 __attribute__((ext_vector_type(8)));
typedef __bf16 b16x8 __attribute__((ext_vector_type(8)));
typedef float f32x4 __attribute__((ext_vector_type(4)));

__device__ inline short f2bf(float f) {
    unsigned u = __float_as_uint(f);
    unsigned r = u + 0x7FFFu + ((u >> 16) & 1u);   // RNE
    return (short)(r >> 16);
}
__device__ inline float bf2f(unsigned short u) {
    return __uint_as_float(((unsigned)u) << 16);
}

// ---------------- CSR build ----------------

__global__ void init_cnt_kernel(int* cnt, int n) {
    int i = blockIdx.x * blockDim.x + threadIdx.x;
    if (i < n) cnt[i] = 0;
}

__global__ void count_kernel(const int* __restrict__ dst, int* __restrict__ cnt, int E) {
    int e = blockIdx.x * blockDim.x + threadIdx.x;
    if (e < E) atomicAdd(&cnt[dst[e]], 1);
}

// Hierarchical scan: per-block scan -> wave scan of block sums -> fixup.
__global__ __launch_bounds__(1024) void blockscan_kernel(const int* __restrict__ cnt,
                                                         int* __restrict__ rp,
                                                         int* __restrict__ bsum, int n) {
    __shared__ int sdata[1024];
    int tid = threadIdx.x;
    int i = blockIdx.x * 1024 + tid;
    int v = (i < n) ? cnt[i] : 0;
    sdata[tid] = v;
    __syncthreads();
    for (int off = 1; off < 1024; off <<= 1) {
        int t = 0;
        if (tid >= off) t = sdata[tid - off];
        __syncthreads();
        sdata[tid] += t;
        __syncthreads();
    }
    if (i < n) rp[i] = sdata[tid] - v;       // local exclusive
    if (tid == 1023) bsum[blockIdx.x] = sdata[1023];
}

__global__ void topscan_kernel(int* bsum, int nb) {
    int lane = threadIdx.x;                   // 64 threads
    int carry = 0;
    for (int base = 0; base < nb; base += 64) {
        int idx = base + lane;
        int orig = (idx < nb) ? bsum[idx] : 0;
        int v = orig;
        for (int off = 1; off < 64; off <<= 1) {
            int t = __shfl_up(v, off, 64);
            if (lane >= off) v += t;
        }
        if (idx < nb) bsum[idx] = carry + v - orig;   // exclusive
        carry += __shfl(v, 63, 64);
    }
}

__global__ __launch_bounds__(1024) void fixup_kernel(int* __restrict__ rp,
                                                     const int* __restrict__ bsum,
                                                     const int* __restrict__ cnt,
                                                     int* __restrict__ cursor,
                                                     float* __restrict__ dinv,
                                                     int n, int E) {
    int i = blockIdx.x * 1024 + threadIdx.x;
    if (i < n) {
        int r = rp[i] + bsum[blockIdx.x];
        rp[i] = r;
        cursor[i] = r;
        dinv[i] = rsqrtf((float)cnt[i] + 1.0f);
    }
    if (i == 0) rp[n] = E;
}

__global__ void fill_kernel(const int* __restrict__ src, const int* __restrict__ dst,
                            int* __restrict__ cursor, const float* __restrict__ dinv,
                            int* __restrict__ csrc, float* __restrict__ cw, int E) {
    int e = blockIdx.x * blockDim.x + threadIdx.x;
    if (e >= E) return;
    int d = dst[e];
    int s = src[e];
    int p = atomicAdd(&cursor[d], 1);
    csrc[p] = s;
    cw[p] = dinv[s] * dinv[d];
}

// ---------------- weight pre-transpose to fragment-ready bf16 ----------------
// Wt chunk layout: [c = k0/32][b = n0/128][nt 0..7][lane 0..63][j 0..7]
//   value = W[c*32 + (lane>>4)*8 + j][b*128 + nt*16 + (lane&15)]

__global__ void make_wt_kernel(const float* __restrict__ W, short* __restrict__ Wt,
                               int K, int N) {
    int idx = blockIdx.x * blockDim.x + threadIdx.x;
    if (idx >= K * N) return;
    int NB = N >> 7;
    int j = idx & 7;
    int l = (idx >> 3) & 63;
    int nt = (idx >> 9) & 7;
    int rest = idx >> 12;
    int b = rest % NB;
    int c = rest / NB;
    int k = c * 32 + (l >> 4) * 8 + j;
    int n = b * 128 + nt * 16 + (l & 15);
    Wt[idx] = f2bf(W[(size_t)k * N + n]);
}

// ---------------- bf16 MFMA GEMM: Cb[MxN](bf16) = A[MxK] @ B[KxN] ----------------
// AT = float (fp32 A, converted in staging) or ushort (bf16 A).
// Block tile 128 x (2*WNT*16), 256 threads = 4 waves, wave tile 64 x (WNT*16).
// Double-buffered LDS, register prefetch, ONE barrier per K-chunk.
// Requires K%32==0, N % (2*WNT*16) == 0.

template<typename AT, int WNT>
__global__ __launch_bounds__(256, 3) void mfma_gemm_kernel(const AT* __restrict__ A,
                                                           const short* __restrict__ Wt,
                                                           unsigned short* __restrict__ Cb,
                                                           int M, int N, int K) {
    constexpr int TB = 2 * WNT;                  // B n-tiles (16 cols each) per block
    constexpr int BPT = TB / 4;                  // B 16-byte loads per thread
    __shared__ b16x8 Asl[2][8 * 64];             // 8 KB each
    __shared__ b16x8 Bsl[2][TB * 64];            // TB KB each

    const int tid = threadIdx.x;
    const int lane = tid & 63;
    const int wave = tid >> 6;
    const int wm = wave & 1;
    const int wn = wave >> 1;
    const int NB = N >> 7;
    const int m0 = blockIdx.y * 128;
    const int n0 = blockIdx.x * (TB * 16);
    const int KC = K >> 5;
    const s16x8* wt = (const s16x8*)Wt;

    f32x4 acc[4][WNT];
#pragma unroll
    for (int i = 0; i < 4; ++i)
#pragma unroll
        for (int j = 0; j < WNT; ++j)
            acc[i][j] = (f32x4){0.f, 0.f, 0.f, 0.f};

    // prefetch registers
    float4 fa[2][2];                              // fp32 A path
    s16x8 ba[2];                                  // bf16 A path
    s16x8 bb[BPT];

    auto load_global = [&](int c) {
        const int k0 = c << 5;
#pragma unroll
        for (int u = 0; u < 2; ++u) {
            int unit = tid + u * 256;             // 0..511
            int r = unit >> 2;                    // 0..127
            int q = unit & 3;                     // k octet
            int grow = m0 + r;
            if constexpr (sizeof(AT) == 4) {
                if (grow < M) {
                    const float* ap = (const float*)&A[(size_t)grow * K + k0 + q * 8];
                    fa[u][0] = *(const float4*)ap;
                    fa[u][1] = *(const float4*)(ap + 4);
                } else {
                    fa[u][0] = make_float4(0.f, 0.f, 0.f, 0.f);
                    fa[u][1] = make_float4(0.f, 0.f, 0.f, 0.f);
                }
            } else {
                if (grow < M) ba[u] = *(const s16x8*)&A[(size_t)grow * K + k0 + q * 8];
                else ba[u] = (s16x8){0, 0, 0, 0, 0, 0, 0, 0};
            }
        }
#pragma unroll
        for (int i = 0; i < BPT; ++i) {
            int t = tid + i * 256;
            int tile = t >> 6;
            int l = t & 63;
            size_t chunk = (size_t)(c * NB + blockIdx.x * (TB >> 3) + (tile >> 3));
            bb[i] = wt[chunk * 512 + (tile & 7) * 64 + l];
        }
    };

    auto stage = [&](int buf) {
#pragma unroll
        for (int u = 0; u < 2; ++u) {
            int unit = tid + u * 256;
            int r = unit >> 2;
            int q = unit & 3;
            s16x8 v;
            if constexpr (sizeof(AT) == 4) {
                v[0] = f2bf(fa[u][0].x); v[1] = f2bf(fa[u][0].y);
                v[2] = f2bf(fa[u][0].z); v[3] = f2bf(fa[u][0].w);
                v[4] = f2bf(fa[u][1].x); v[5] = f2bf(fa[u][1].y);
                v[6] = f2bf(fa[u][1].z); v[7] = f2bf(fa[u][1].w);
            } else {
                v = ba[u];
            }
            Asl[buf][(r >> 4) * 64 + q * 16 + (r & 15)] = __builtin_bit_cast(b16x8, v);
        }
#pragma unroll
        for (int i = 0; i < BPT; ++i) {
            int t = tid + i * 256;
            Bsl[buf][t] = __builtin_bit_cast(b16x8, bb[i]);
        }
    };

    load_global(0);
    stage(0);
    __syncthreads();

    for (int c = 0; c < KC; ++c) {
        const int cur = c & 1;
        if (c + 1 < KC) load_global(c + 1);       // global loads in flight during MFMA

        b16x8 areg[4], breg[WNT];
#pragma unroll
        for (int i = 0; i < 4; ++i) areg[i] = Asl[cur][(wm * 4 + i) * 64 + lane];
#pragma unroll
        for (int j = 0; j < WNT; ++j) breg[j] = Bsl[cur][(wn * WNT + j) * 64 + lane];
#pragma unroll
        for (int i = 0; i < 4; ++i)
#pragma unroll
            for (int j = 0; j < WNT; ++j)
                acc[i][j] = __builtin_amdgcn_mfma_f32_16x16x32_bf16(areg[i], breg[j], acc[i][j], 0, 0, 0);

        if (c + 1 < KC) stage(cur ^ 1);           // consume prefetch -> other buffer
        __syncthreads();
    }

    const int quad = lane >> 4;
    const int nl = lane & 15;
#pragma unroll
    for (int i = 0; i < 4; ++i) {
        int rbase = m0 + wm * 64 + i * 16 + quad * 4;
#pragma unroll
        for (int j = 0; j < WNT; ++j) {
            int col = n0 + wn * (WNT * 16) + j * 16 + nl;
#pragma unroll
            for (int r = 0; r < 4; ++r) {
                int row = rbase + r;
                if (row < M) Cb[(size_t)row * N + col] = (unsigned short)f2bf(acc[i][j][r]);
            }
        }
    }
}

// ---------------- aggregation, bf16 in ----------------
// Wave per node. C=256: lane handles 4 channels (ushort4, 8B loads). ReLU, bf16 out.

__global__ __launch_bounds__(256) void agg256_kernel(const unsigned short* __restrict__ h,
                                                     const int* __restrict__ rp,
                                                     const int* __restrict__ csrc,
                                                     const float* __restrict__ cw,
                                                     const float* __restrict__ dinv,
                                                     const float* __restrict__ bias,
                                                     unsigned short* __restrict__ out, int n) {
    int node = blockIdx.x * 4 + (threadIdx.x >> 6);
    int lane = threadIdx.x & 63;
    if (node >= n) return;
    const ushort4* hp = (const ushort4*)h;       // 64 per row
    float di = dinv[node];
    float ws = di * di;
    ushort4 sv = hp[(size_t)node * 64 + lane];
    float a0 = ws * bf2f(sv.x), a1 = ws * bf2f(sv.y), a2 = ws * bf2f(sv.z), a3 = ws * bf2f(sv.w);
    int e = rp[node], e1 = rp[node + 1];
    for (; e + 1 < e1; e += 2) {
        int s0 = csrc[e], s1 = csrc[e + 1];
        float w0 = cw[e], w1 = cw[e + 1];
        ushort4 v0 = hp[(size_t)s0 * 64 + lane];
        ushort4 v1 = hp[(size_t)s1 * 64 + lane];
        a0 += w0 * bf2f(v0.x) + w1 * bf2f(v1.x);
        a1 += w0 * bf2f(v0.y) + w1 * bf2f(v1.y);
        a2 += w0 * bf2f(v0.z) + w1 * bf2f(v1.z);
        a3 += w0 * bf2f(v0.w) + w1 * bf2f(v1.w);
    }
    if (e < e1) {
        int s0 = csrc[e];
        float w0 = cw[e];
        ushort4 v0 = hp[(size_t)s0 * 64 + lane];
        a0 += w0 * bf2f(v0.x); a1 += w0 * bf2f(v0.y);
        a2 += w0 * bf2f(v0.z); a3 += w0 * bf2f(v0.w);
    }
    float4 bv = *(const float4*)&bias[lane * 4];
    a0 = fmaxf(a0 + bv.x, 0.f); a1 = fmaxf(a1 + bv.y, 0.f);
    a2 = fmaxf(a2 + bv.z, 0.f); a3 = fmaxf(a3 + bv.w, 0.f);
    ushort4 ov;
    ov.x = (unsigned short)f2bf(a0); ov.y = (unsigned short)f2bf(a1);
    ov.z = (unsigned short)f2bf(a2); ov.w = (unsigned short)f2bf(a3);
    ((ushort4*)out)[(size_t)node * 64 + lane] = ov;
}

// C=128: lane handles 2 channels (uint loads). Fused: a2 = relu(agg+b2); z = a2 @ W3 (128x2).
__global__ __launch_bounds__(256) void agg128_w3_kernel(const unsigned short* __restrict__ h,
                                                        const int* __restrict__ rp,
                                                        const int* __restrict__ csrc,
                                                        const float* __restrict__ cw,
                                                        const float* __restrict__ dinv,
                                                        const float* __restrict__ b2,
                                                        const float* __restrict__ W3,
                                                        float* __restrict__ z, int n) {
    int node = blockIdx.x * 4 + (threadIdx.x >> 6);
    int lane = threadIdx.x & 63;
    if (node >= n) return;
    const unsigned* hp = (const unsigned*)h;     // 64 uints per row (2 bf16 each)
    float di = dinv[node];
    float ws = di * di;
    unsigned sv = hp[(size_t)node * 64 + lane];
    float a0 = ws * __uint_as_float(sv << 16);
    float a1 = ws * __uint_as_float(sv & 0xFFFF0000u);
    int e = rp[node], e1 = rp[node + 1];
    for (; e + 1 < e1; e += 2) {
        int s0 = csrc[e], s1 = csrc[e + 1];
        float w0 = cw[e], w1 = cw[e + 1];
        unsigned v0 = hp[(size_t)s0 * 64 + lane];
        unsigned v1 = hp[(size_t)s1 * 64 + lane];
        a0 += w0 * __uint_as_float(v0 << 16) + w1 * __uint_as_float(v1 << 16);
        a1 += w0 * __uint_as_float(v0 & 0xFFFF0000u) + w1 * __uint_as_float(v1 & 0xFFFF0000u);
    }
    if (e < e1) {
        int s0 = csrc[e];
        float w0 = cw[e];
        unsigned v0 = hp[(size_t)s0 * 64 + lane];
        a0 += w0 * __uint_as_float(v0 << 16);
        a1 += w0 * __uint_as_float(v0 & 0xFFFF0000u);
    }
    float2 bv = *(const float2*)&b2[lane * 2];
    a0 = fmaxf(a0 + bv.x, 0.f);
    a1 = fmaxf(a1 + bv.y, 0.f);
    // W3 row-major [128][2]; channels 2*lane, 2*lane+1
    float4 wv = *(const float4*)&W3[lane * 4];
    float z0 = a0 * wv.x + a1 * wv.z;
    float z1 = a0 * wv.y + a1 * wv.w;
    for (int off = 32; off > 0; off >>= 1) {
        z0 += __shfl_down(z0, off, 64);
        z1 += __shfl_down(z1, off, 64);
    }
    if (lane == 0) {
        z[2 * (size_t)node] = z0;
        z[2 * (size_t)node + 1] = z1;
    }
}

// Final: out = sigmoid(Ahat z + b3), z fp32 [n][2].
__global__ void agg3_kernel(const float* __restrict__ z, const int* __restrict__ rp,
                            const int* __restrict__ csrc, const float* __restrict__ cw,
                            const float* __restrict__ dinv, const float* __restrict__ bias,
                            float* __restrict__ out, int n) {
    int node = blockIdx.x * blockDim.x + threadIdx.x;
    if (node >= n) return;
    float di = dinv[node];
    float a0 = di * di * z[2 * (size_t)node];
    float a1 = di * di * z[2 * (size_t)node + 1];
    int e1 = rp[node + 1];
    for (int e = rp[node]; e < e1; ++e) {
        int s = csrc[e];
        float w = cw[e];
        a0 += w * z[2 * (size_t)s];
        a1 += w * z[2 * (size_t)s + 1];
    }
    a0 += bias[0];
    a1 += bias[1];
    out[2 * (size_t)node]     = 1.f / (1.f + __expf(-a0));
    out[2 * (size_t)node + 1] = 1.f / (1.f + __expf(-a1));
}

// ---------------- launch ----------------

extern "C" void kernel_launch(void* const* d_in, const int* in_sizes, int n_in,
                              void* d_out, int out_size, void* d_ws, size_t ws_size,
                              hipStream_t stream) {
    const float* x  = (const float*)d_in[0];
    const int*   ei = (const int*)d_in[1];
    const float* W1 = (const float*)d_in[2];
    const float* b1 = (const float*)d_in[3];
    const float* W2 = (const float*)d_in[4];
    const float* b2 = (const float*)d_in[5];
    const float* W3 = (const float*)d_in[6];
    const float* b3 = (const float*)d_in[7];
    float* out = (float*)d_out;

    const int E  = in_sizes[1] / 2;
    const int C1 = in_sizes[3];              // 256
    const int C2 = in_sizes[5];              // 128
    const int K1 = in_sizes[2] / C1;         // 768
    const int N  = in_sizes[0] / K1;         // 50000

    const int* srcv = ei;
    const int* dstv = ei + E;

    char* p = (char*)d_ws;
    auto carve = [&](size_t bytes) {
        char* r = p;
        p += (bytes + 255) & ~(size_t)255;
        return r;
    };
    int*   cnt    = (int*)carve((size_t)N * 4);
    int*   rp     = (int*)carve((size_t)(N + 1) * 4);
    int*   cursor = (int*)carve((size_t)N * 4);
    float* dinv   = (float*)carve((size_t)N * 4);
    int*   bsum   = (int*)carve(1024 * 4);
    int*   csrc   = (int*)carve((size_t)E * 4);
    float* cw     = (float*)carve((size_t)E * 4);
    short* Wt1    = (short*)carve((size_t)K1 * C1 * 2);
    short* Wt2    = (short*)carve((size_t)C1 * C2 * 2);
    unsigned short* hA = (unsigned short*)carve((size_t)N * C1 * 2);
    unsigned short* hB = (unsigned short*)carve((size_t)N * C1 * 2);
    float* zbuf   = (float*)carve((size_t)N * 2 * 4);

    const int nb = (N + 1023) / 1024;

    // CSR build
    init_cnt_kernel<<<(N + 255) / 256, 256, 0, stream>>>(cnt, N);
    count_kernel<<<(E + 255) / 256, 256, 0, stream>>>(dstv, cnt, E);
    blockscan_kernel<<<nb, 1024, 0, stream>>>(cnt, rp, bsum, N);
    topscan_kernel<<<1, 64, 0, stream>>>(bsum, nb);
    fixup_kernel<<<nb, 1024, 0, stream>>>(rp, bsum, cnt, cursor, dinv, N, E);
    fill_kernel<<<(E + 255) / 256, 256, 0, stream>>>(srcv, dstv, cursor, dinv, csrc, cw, E);

    // Weight pre-transpose (fragment-ready bf16)
    make_wt_kernel<<<(K1 * C1 + 255) / 256, 256, 0, stream>>>(W1, Wt1, K1, C1);
    make_wt_kernel<<<(C1 * C2 + 255) / 256, 256, 0, stream>>>(W2, Wt2, C1, C2);

    // Layer 1: h1 = x @ W1 (128x128 tiles, 782 blocks) ; a1 = relu(Ahat h1 + b1)
    dim3 g1(C1 / 128, (N + 127) / 128);
    mfma_gemm_kernel<float, 4><<<g1, 256, 0, stream>>>(x, Wt1, hA, N, C1, K1);
    agg256_kernel<<<(N + 3) / 4, 256, 0, stream>>>(hA, rp, csrc, cw, dinv, b1, hB, N);

    // Layer 2: h2 = a1 @ W2 ; fused a2 = relu(Ahat h2 + b2), z = a2 @ W3
    dim3 g2(C2 / 128, (N + 127) / 128);
    mfma_gemm_kernel<unsigned short, 4><<<g2, 256, 0, stream>>>(hB, Wt2, hA, N, C2, C1);
    agg128_w3_kernel<<<(N + 3) / 4, 256, 0, stream>>>(hA, rp, csrc, cw, dinv, b2, W3, zbuf, N);

    // Layer 3 aggregation + sigmoid
    agg3_kernel<<<(N + 255) / 256, 256, 0, stream>>>(zbuf, rp, csrc, cw, dinv, b3, out, N);
}